// Round 2
// baseline (652.763 us; speedup 1.0000x reference)
//
#include <hip/hip_runtime.h>

// GAT 3-layer forward on MI355X — round 14.
// vs round 13 (649.7us, REGRESSION): R13 put the feat8 gather ADDRESS behind a
// ds_bpermute (sj = shfl(sA)) — LDS latency on the address path cut memory-level
// parallelism from 16 to 4 loads in flight (hbm_gbps 2257->1686 on aggregate4).
// R14 keeps R13's wins (8B feat loads, packed v_pk_fma_f32, wide epilogue) and
// restores a load-based address path: group g owns CONTIGUOUS edges 4g..4g+3,
// fetched as one per-lane int4 from csr (4 distinct 16B segments/wave, L1
// broadcast). Phase-A sA is a 3-cndmask select from the same int4. Only the
// multiplier 'aw' still crosses lanes (1 bpermute/iter, off the address path).

typedef __attribute__((ext_vector_type(8))) short s8v;
typedef __attribute__((ext_vector_type(4))) float f4v;
typedef __attribute__((ext_vector_type(2))) float f2v;
typedef __attribute__((ext_vector_type(2))) _Float16 h2;
typedef __attribute__((ext_vector_type(4))) _Float16 h4;
typedef __attribute__((ext_vector_type(8))) _Float16 h8;

__device__ __forceinline__ unsigned short f2bf(float f) {
  unsigned int x = __float_as_uint(f);
  x += 0x7fffu + ((x >> 16) & 1u);          // RTNE
  return (unsigned short)(x >> 16);
}
__device__ __forceinline__ float bf2f(unsigned short u) {
  return __uint_as_float(((unsigned int)u) << 16);
}
__device__ __forceinline__ unsigned short f2h(float f) {
  _Float16 h = (_Float16)f;
  return __builtin_bit_cast(unsigned short, h);
}
__device__ __forceinline__ unsigned char f2fp8(float v) {
  return (unsigned char)(__builtin_amdgcn_cvt_pk_fp8_f32(v, v, 0, false) & 0xff);
}
__device__ __forceinline__ float lrelu(float x) { return fmaxf(x, 0.2f * x); }
__device__ __forceinline__ float elu1(float x) { return x > 0.f ? x : expm1f(x); }

// ---------------- per-node degree histogram (for rsp) ----------------
__global__ __launch_bounds__(256) void hist_k(const int* __restrict__ dst, int* __restrict__ counts, int E) {
  int t = blockIdx.x * 256 + threadIdx.x;
  if (t < E) atomicAdd(&counts[dst[t]], 1);
}

// scan1: exclusive prefix over counts ROUNDED UP to 16 (padded row starts)
__global__ __launch_bounds__(256) void scan1(const int* __restrict__ counts, int* __restrict__ rsp,
                                             int* __restrict__ bsum, int Nn) {
  __shared__ int s[256];
  int t = threadIdx.x;
  int base = blockIdx.x * 1024 + t * 4;
  int v0 = (base + 0 < Nn) ? ((counts[base + 0] + 15) & ~15) : 0;
  int v1 = (base + 1 < Nn) ? ((counts[base + 1] + 15) & ~15) : 0;
  int v2 = (base + 2 < Nn) ? ((counts[base + 2] + 15) & ~15) : 0;
  int v3 = (base + 3 < Nn) ? ((counts[base + 3] + 15) & ~15) : 0;
  s[t] = v0 + v1 + v2 + v3;
  __syncthreads();
  for (int off = 1; off < 256; off <<= 1) {
    int xv = (t >= off) ? s[t - off] : 0;
    __syncthreads();
    s[t] += xv;
    __syncthreads();
  }
  int excl = t ? s[t - 1] : 0;
  if (t == 255) bsum[blockIdx.x] = s[255];
  if (base + 0 < Nn) { rsp[base + 0] = excl; excl += v0; }
  if (base + 1 < Nn) { rsp[base + 1] = excl; excl += v1; }
  if (base + 2 < Nn) { rsp[base + 2] = excl; excl += v2; }
  if (base + 3 < Nn) { rsp[base + 3] = excl; }
}

// pscan1: plain (no rounding) exclusive prefix — for the bucket-segment table
__global__ __launch_bounds__(256) void pscan1(const int* __restrict__ in, int* __restrict__ out,
                                              int* __restrict__ bsum, int Nn) {
  __shared__ int s[256];
  int t = threadIdx.x;
  int base = blockIdx.x * 1024 + t * 4;
  int v0 = (base + 0 < Nn) ? in[base + 0] : 0;
  int v1 = (base + 1 < Nn) ? in[base + 1] : 0;
  int v2 = (base + 2 < Nn) ? in[base + 2] : 0;
  int v3 = (base + 3 < Nn) ? in[base + 3] : 0;
  s[t] = v0 + v1 + v2 + v3;
  __syncthreads();
  for (int off = 1; off < 256; off <<= 1) {
    int xv = (t >= off) ? s[t - off] : 0;
    __syncthreads();
    s[t] += xv;
    __syncthreads();
  }
  int excl = t ? s[t - 1] : 0;
  if (t == 255) bsum[blockIdx.x] = s[255];
  if (base + 0 < Nn) { out[base + 0] = excl; excl += v0; }
  if (base + 1 < Nn) { out[base + 1] = excl; excl += v1; }
  if (base + 2 < Nn) { out[base + 2] = excl; excl += v2; }
  if (base + 3 < Nn) { out[base + 3] = excl; }
}

__global__ __launch_bounds__(128) void scan2(int* __restrict__ bsum, int nb) {
  __shared__ int s[128];
  int t = threadIdx.x;
  s[t] = (t < nb) ? bsum[t] : 0;
  __syncthreads();
  for (int off = 1; off < 128; off <<= 1) {
    int xv = (t >= off) ? s[t - off] : 0;
    __syncthreads();
    s[t] += xv;
    __syncthreads();
  }
  if (t < nb) bsum[t] = t ? s[t - 1] : 0;
}

__global__ __launch_bounds__(256) void scan3(int* __restrict__ arr, const int* __restrict__ bsum, int Nn) {
  int t = blockIdx.x * 256 + threadIdx.x;
  if (t < Nn) arr[t] += bsum[t >> 10];
}

// ---------------- pass 1: per-(block,bucket) histogram; bucket = dst>>8 ----------------
__global__ __launch_bounds__(256) void bhist_k(const int* __restrict__ dst, int* __restrict__ bhist,
                                               int E, int NB, int chunk) {
  __shared__ int h[512];
  for (int b = threadIdx.x; b < NB; b += 256) h[b] = 0;
  __syncthreads();
  int e0 = blockIdx.x * chunk;
  int e1 = min(E, e0 + chunk);
  for (int e = e0 + threadIdx.x; e < e1; e += 256) atomicAdd(&h[dst[e] >> 8], 1);
  __syncthreads();
  for (int b = threadIdx.x; b < NB; b += 256)
    bhist[(size_t)b * gridDim.x + blockIdx.x] = h[b];
}

// ---------------- pass 2: scatter edges into private (block,bucket) segments ----------------
__global__ __launch_bounds__(256) void bscatter_k(const int* __restrict__ src, const int* __restrict__ dst,
                                                  const int* __restrict__ seg, int2* __restrict__ ebuf,
                                                  int E, int NB, int chunk) {
  __shared__ int cur[512];
  for (int b = threadIdx.x; b < NB; b += 256)
    cur[b] = seg[(size_t)b * gridDim.x + blockIdx.x];
  __syncthreads();
  int e0 = blockIdx.x * chunk;
  int e1 = min(E, e0 + chunk);
  for (int e = e0 + threadIdx.x; e < e1; e += 256) {
    int d = dst[e];
    int pos = atomicAdd(&cur[d >> 8], 1);
    int2 v; v.x = src[e]; v.y = d;
    ebuf[pos] = v;
  }
}

// ---------------- pass 3: per-bucket final scatter (one block per 256-node bucket) ----------------
__global__ __launch_bounds__(256) void fscatter_k(const int2* __restrict__ ebuf, const int* __restrict__ seg,
                                                  const int* __restrict__ rsp, int* __restrict__ csr_src,
                                                  int E, int NB, int P2B, int Nn) {
  __shared__ int cur[256];
  int b = blockIdx.x;
  int node0 = b << 8;
  int node = node0 + threadIdx.x;
  if (node < Nn) cur[threadIdx.x] = rsp[node];
  __syncthreads();
  int bstart = seg[(size_t)b * P2B];
  int bend = (b + 1 < NB) ? seg[(size_t)(b + 1) * P2B] : E;
  for (int e = bstart + threadIdx.x; e < bend; e += 256) {
    int2 sd = ebuf[e];
    int pos = atomicAdd(&cur[sd.y - node0], 1);
    csr_src[pos] = sd.x;
  }
}

// ---------------- fused weight pack (all 3 layers, one launch) ----------------
__device__ __forceinline__ void pack_one(const float* W, const float* al, const float* ar,
                                         const float* resW, unsigned short* out,
                                         int K, int M, int BF, int H, int RES0, int t) {
  int c = t / K, k = t - c * K;
  float v = 0.f;
  if (c < BF) {
    v = W[k * BF + c];
  } else if (c < BF + H) {
    int h = c - BF;
    float s = 0.f;
    for (int d = 0; d < 32; d++) s += W[k * BF + h * 32 + d] * al[h * 32 + d];
    v = s;
  } else if (c < BF + 2 * H) {
    int h = c - BF - H;
    float s = 0.f;
    for (int d = 0; d < 32; d++) s += W[k * BF + h * 32 + d] * ar[h * 32 + d];
    v = s;
  } else if (c >= RES0) {
    v = resW[k * (M - RES0) + (c - RES0)];
  }
  unsigned short hi = f2bf(v);
  out[c * K + k] = hi;
  out[M * K + c * K + k] = f2bf(v - bf2f(hi));
}

__global__ __launch_bounds__(256) void fill_all(const float* __restrict__ W0, const float* __restrict__ al0,
                                                const float* __restrict__ ar0,
                                                const float* __restrict__ W1, const float* __restrict__ al1,
                                                const float* __restrict__ ar1, const float* __restrict__ resW1,
                                                const float* __restrict__ W2, const float* __restrict__ al2,
                                                const float* __restrict__ ar2, const float* __restrict__ resW2,
                                                unsigned short* __restrict__ w0t, unsigned short* __restrict__ w1t,
                                                unsigned short* __restrict__ w2t) {
  const int n0 = 144 * 64, n1 = 272 * 128, n2 = 80 * 128;
  int t = blockIdx.x * 256 + threadIdx.x;
  if (t < n0) {
    pack_one(W0, al0, ar0, nullptr, w0t, 64, 144, 128, 4, 144, t);
  } else if (t < n0 + n1) {
    pack_one(W1, al1, ar1, resW1, w1t, 128, 272, 128, 4, 144, t - n0);
  } else if (t < n0 + n1 + n2) {
    pack_one(W2, al2, ar2, resW2, w2t, 128, 80, 32, 1, 48, t - n0 - n1);
  }
}

// ---------------- cmw[col] = invN * colsum @ (W_hi + W_lo)  (rank-1 PairNorm fold) ----------------
__global__ __launch_bounds__(256) void cmw_k(const float* __restrict__ colsum,
                                             const unsigned short* __restrict__ wt,
                                             float* __restrict__ cmw, int K, int M, float invN) {
  int c = blockIdx.x * 256 + threadIdx.x;
  if (c >= M) return;
  float s = 0.f;
  for (int k = 0; k < K; k++)
    s += colsum[k] * (bf2f(wt[c * K + k]) + bf2f(wt[(size_t)M * K + c * K + k]));
  cmw[c] = s * invN;
}

// ---------------- GEMM: A[N,K] @ Bt[M,K](bf16 hi+lo); epilogue: -cmw, route cols ----------------
template <int K, int M, int R, int BF, int H, int RES0, bool AF32, bool CMW>
__global__ __launch_bounds__(256) void gemm_bf16(const void* __restrict__ Av,
                                                 const unsigned short* __restrict__ Bt,
                                                 const float* __restrict__ cmw,
                                                 unsigned char* __restrict__ feat8,
                                                 float* __restrict__ el, float* __restrict__ er,
                                                 unsigned short* __restrict__ resh, int nRowTiles) {
  int wv = (int)((blockIdx.x * blockDim.x + threadIdx.x) >> 6);
  int tile0 = wv * R;
  if (tile0 >= nRowTiles) return;
  int lane = threadIdx.x & 63;
  int r = lane & 15, q = lane >> 4;
  s8v afrag[R][K / 32];
#pragma unroll
  for (int rr = 0; rr < R; rr++) {
    if constexpr (AF32) {
      const float* arow = (const float*)Av + (size_t)((tile0 + rr) * 16 + r) * K + q * 8;
#pragma unroll
      for (int kk = 0; kk < K / 32; kk++) {
        s8v v;
#pragma unroll
        for (int j = 0; j < 8; j++) v[j] = (short)f2bf(arow[kk * 32 + j]);
        afrag[rr][kk] = v;
      }
    } else {
      const unsigned short* arow = (const unsigned short*)Av + (size_t)((tile0 + rr) * 16 + r) * K + q * 8;
#pragma unroll
      for (int kk = 0; kk < K / 32; kk++) afrag[rr][kk] = *(const s8v*)(arow + kk * 32);
    }
  }
#pragma unroll
  for (int ct = 0; ct < M / 16; ct++) {
    const unsigned short* brow = Bt + (size_t)(ct * 16 + r) * K + q * 8;
    s8v bhi[K / 32], blo[K / 32];
#pragma unroll
    for (int kk = 0; kk < K / 32; kk++) {
      bhi[kk] = *(const s8v*)(brow + kk * 32);
      blo[kk] = *(const s8v*)(brow + (size_t)M * K + kk * 32);
    }
    int col = ct * 16 + r;
    float cmwv = 0.f;
    if constexpr (CMW) cmwv = cmw[col];
#pragma unroll
    for (int rr = 0; rr < R; rr++) {
      f4v acc = {0.f, 0.f, 0.f, 0.f};
#pragma unroll
      for (int kk = 0; kk < K / 32; kk++) {
        acc = __builtin_amdgcn_mfma_f32_16x16x32_bf16(afrag[rr][kk], bhi[kk], acc, 0, 0, 0);
        acc = __builtin_amdgcn_mfma_f32_16x16x32_bf16(afrag[rr][kk], blo[kk], acc, 0, 0, 0);
      }
      int row0 = (tile0 + rr) * 16 + q * 4;
#pragma unroll
      for (int i = 0; i < 4; i++) {
        float v = acc[i] - cmwv;
        size_t row = (size_t)(row0 + i);
        if (col < BF) {
          feat8[row * BF + col] = f2fp8(v);
        } else if (col < BF + H) {
          el[row * H + (col - BF)] = v;
        } else if (col < BF + 2 * H) {
          er[row * H + (col - BF - H)] = v;
        } else if (RES0 < M && col >= RES0) {
          resh[row * (M - RES0) + (col - RES0)] = f2h(v);
        }
      }
    }
  }
}

// ---------------- fused single-pass aggregation H=4 (fp8 feat table) ----------------
// Round 14 lane mapping: group g = lane>>4 owns CONTIGUOUS edges 4g..4g+3 of each
// chunk; sj4 = one per-lane int4 load of csp[4g..4g+3] (4 distinct 16B segs/wave,
// L1 broadcast) — feat8 addresses depend only on loads, never on bpermute.
// Phase-A edge index slot=lane>>2 satisfies slot>>2 == g, so sA is a 3-cndmask
// select from sj4. l16 = lane&15 owns dims 8*l16..8*l16+7 (head hh=l16>>2), one
// 8B uint2 per row. Multiplier aw arrives via 1 bpermute/iter (off address path).
// float2 accumulators -> v_pk_fma_f32; cross-group butterfly at the end.
template <int MODE>
__global__ __launch_bounds__(256) void aggregate4(const unsigned char* __restrict__ feat8,
                                                  const float* __restrict__ el4,
                                                  const float* __restrict__ er4,
                                                  const int* __restrict__ csr_src,
                                                  const int* __restrict__ rsp,
                                                  const int* __restrict__ counts,
                                                  const unsigned short* __restrict__ resh,
                                                  unsigned short* __restrict__ vbf,
                                                  float* __restrict__ rnrm, int Nn) {
  int n = (int)((blockIdx.x * blockDim.x + threadIdx.x) >> 6);
  if (n >= Nn) return;
  int lane = threadIdx.x & 63;
  int start = __builtin_amdgcn_readfirstlane(rsp[n]);
  int deg = __builtin_amdgcn_readfirstlane(counts[n]);
  int chunks = (deg + 15) >> 4;
  int slot = lane >> 2, h = lane & 3;
  int tsel = slot & 3;                 // which element of sj4 is this lane's phase-A edge
  float ern = er4[(size_t)n * 4 + h];
  int g = lane >> 4;                   // group: edges 4g..4g+3
  int l16 = lane & 15;                 // dims 8*l16 .. 8*l16+7
  int hh = l16 >> 2;                   // head of this lane's dims
  int awbase = (g << 4) | hh;          // phase-A lane of (edge 4g+t, head hh) is awbase + 4t
  unsigned dby = (unsigned)l16 << 3;   // byte offset into 128B fp8 row
  f2v a0 = {0.f, 0.f}, a1 = {0.f, 0.f}, a2 = {0.f, 0.f}, a3 = {0.f, 0.f};
  float dsum = 0.f;
  for (int c = 0; c < chunks; c++) {
    const int* csp = csr_src + start + (c << 4);
    // one 16B load delivers this group's 4 src indices (addresses: pure load path)
    int4 sj4 = *(const int4*)(csp + (g << 2));
    // phase A: one (edge,head) per lane; edge = slot = 4g + tsel
    int sA = tsel == 0 ? sj4.x : tsel == 1 ? sj4.y : tsel == 2 ? sj4.z : sj4.w;
    float exv = 0.f;
    if (((c << 4) + slot) < deg) {
      float e = el4[(size_t)sA * 4 + h] + ern;
      exv = __expf(fmaxf(e, 0.2f * e));
    }
    dsum += exv;
    // phase B: 4 rows per chunk; this group's edge at step t is 4g+t
#pragma unroll
    for (int t = 0; t < 4; t++) {
      int sj = t == 0 ? sj4.x : t == 1 ? sj4.y : t == 2 ? sj4.z : sj4.w;
      float aw = __shfl(exv, awbase + (t << 2));   // multiplier only — not on addr path
      f2v aw2 = {aw, aw};
      uint2 u = *(const uint2*)(feat8 + (((unsigned)sj << 7) + dby));
      f2v f0 = __builtin_amdgcn_cvt_pk_f32_fp8((int)u.x, false);
      f2v f1 = __builtin_amdgcn_cvt_pk_f32_fp8((int)u.x, true);
      f2v f2 = __builtin_amdgcn_cvt_pk_f32_fp8((int)u.y, false);
      f2v f3 = __builtin_amdgcn_cvt_pk_f32_fp8((int)u.y, true);
      a0 = __builtin_elementwise_fma(f0, aw2, a0);
      a1 = __builtin_elementwise_fma(f1, aw2, a1);
      a2 = __builtin_elementwise_fma(f2, aw2, a2);
      a3 = __builtin_elementwise_fma(f3, aw2, a3);
    }
  }
  // reduce partials across the 4 edge-groups (lanes l16, l16+16, l16+32, l16+48)
#pragma unroll
  for (int off = 16; off < 64; off <<= 1) {
    a0[0] += __shfl_xor(a0[0], off); a0[1] += __shfl_xor(a0[1], off);
    a1[0] += __shfl_xor(a1[0], off); a1[1] += __shfl_xor(a1[1], off);
    a2[0] += __shfl_xor(a2[0], off); a2[1] += __shfl_xor(a2[1], off);
    a3[0] += __shfl_xor(a3[0], off); a3[1] += __shfl_xor(a3[1], off);
  }
  // per-head denominator totals: after butterfly, lane l holds head (l&3) total
#pragma unroll
  for (int off = 4; off < 64; off <<= 1) dsum += __shfl_xor(dsum, off);
  float inv = dsum > 0.f ? 1.f / dsum : 0.f;
  float invh = __shfl(inv, hh);
  float va[8] = {a0[0], a0[1], a1[0], a1[1], a2[0], a2[1], a3[0], a3[1]};
  if (MODE == 1) {
    h8 rr = *(const h8*)(resh + (size_t)n * 128 + (l16 << 3));
#pragma unroll
    for (int k = 0; k < 8; k++) va[k] = elu1(elu1(va[k] * invh + (float)rr[k]));
  } else {
#pragma unroll
    for (int k = 0; k < 8; k++) va[k] = elu1(va[k] * invh);
  }
  float ss = 0.f;
#pragma unroll
  for (int k = 0; k < 8; k++) ss = fmaf(va[k], va[k], ss);
#pragma unroll
  for (int off = 1; off < 16; off <<= 1) ss += __shfl_xor(ss, off);
  float rn = sqrtf(1e-6f + ss);
  float ri = 1.f / rn;
  if (lane < 16) {
    uint4 pk;
    pk.x = (unsigned)f2bf(va[0] * ri) | ((unsigned)f2bf(va[1] * ri) << 16);
    pk.y = (unsigned)f2bf(va[2] * ri) | ((unsigned)f2bf(va[3] * ri) << 16);
    pk.z = (unsigned)f2bf(va[4] * ri) | ((unsigned)f2bf(va[5] * ri) << 16);
    pk.w = (unsigned)f2bf(va[6] * ri) | ((unsigned)f2bf(va[7] * ri) << 16);
    *(uint4*)((char*)vbf + ((size_t)n << 8) + ((unsigned)l16 << 4)) = pk;
  }
  if (lane == 0) rnrm[n] = rn;
}

// ---------------- fused single-pass aggregation H=1 (layer 2, fp8 table) ----------------
// Round 14: group g = lane>>3 owns contiguous edges 2g,2g+1; int2 load of
// csp[2g..2g+1] keeps feat addresses on the load path. aw via bpermute only.
__global__ __launch_bounds__(256) void aggregate1(const unsigned char* __restrict__ feat8,
                                                  const float* __restrict__ el1,
                                                  const float* __restrict__ er1,
                                                  const int* __restrict__ csr_src,
                                                  const int* __restrict__ rsp,
                                                  const int* __restrict__ counts,
                                                  const unsigned short* __restrict__ res2h,
                                                  float* __restrict__ out2, int Nn) {
  int n = (int)((blockIdx.x * blockDim.x + threadIdx.x) >> 6);
  if (n >= Nn) return;
  int lane = threadIdx.x & 63;
  int start = __builtin_amdgcn_readfirstlane(rsp[n]);
  int deg = __builtin_amdgcn_readfirstlane(counts[n]);
  int chunks = (deg + 15) >> 4;
  int l16 = lane & 15;
  float ern = er1[n];
  int g = lane >> 3;                          // 8 edge groups; group g owns edges 2g,2g+1
  unsigned dofs4 = (unsigned)(lane & 7) << 2; // byte offset into 32B fp8 row
  f2v acc01 = {0.f, 0.f}, acc23 = {0.f, 0.f};
  float dsum = 0.f;
  for (int c = 0; c < chunks; c++) {
    const int* csp = csr_src + start + (c << 4);
    int2 sj2 = *(const int2*)(csp + (g << 1));  // this group's 2 src indices
    int sA = (l16 & 1) ? __shfl(sj2.y, lane >> 1) : __shfl(sj2.x, lane >> 1);
    // NOTE: sA only feeds el1 (weight), not an address; recover from sj2 of the
    // group that owns edge l16: group l16>>1, element l16&1. Source lane of that
    // group's int2 is any lane with g==l16>>1, i.e. lane (l16>>1)<<3 — but shfl
    // source must be uniform-per-dest-lane; (lane>>1) is wrong. Use direct load:
    sA = csp[l16];
    float exv = 0.f;
    if (((c << 4) + l16) < deg) exv = __expf(lrelu(el1[sA] + ern));
    dsum += exv;
#pragma unroll
    for (int t = 0; t < 2; t++) {
      int j = (g << 1) + t;
      int sj = t ? sj2.y : sj2.x;
      float aw = __shfl(exv, j);                // multiplier only
      f2v aw2 = {aw, aw};
      unsigned int u = *(const unsigned int*)(feat8 + (((unsigned)sj << 5) + dofs4));
      f2v fa = __builtin_amdgcn_cvt_pk_f32_fp8((int)u, false);
      f2v fb = __builtin_amdgcn_cvt_pk_f32_fp8((int)u, true);
      acc01 = __builtin_elementwise_fma(fa, aw2, acc01);
      acc23 = __builtin_elementwise_fma(fb, aw2, acc23);
    }
  }
#pragma unroll
  for (int off = 1; off < 16; off <<= 1) dsum += __shfl_xor(dsum, off);
  float inv = dsum > 0.f ? 1.f / dsum : 0.f;
#pragma unroll
  for (int off = 8; off < 64; off <<= 1) {
    acc01[0] += __shfl_xor(acc01[0], off);
    acc01[1] += __shfl_xor(acc01[1], off);
    acc23[0] += __shfl_xor(acc23[0], off);
    acc23[1] += __shfl_xor(acc23[1], off);
  }
  if (lane < 8) {
    h4 rr = *(const h4*)(res2h + (size_t)n * 32 + (lane << 2));
    float4 o;
    o.x = acc01[0] * inv + (float)rr[0];
    o.y = acc01[1] * inv + (float)rr[1];
    o.z = acc23[0] * inv + (float)rr[2];
    o.w = acc23[1] * inv + (float)rr[3];
    *(float4*)(out2 + (size_t)n * 32 + (lane << 2)) = o;
  }
}

// ---------------- colsum of raw v = vbf * rnrm (PairNorm colmean numerator) ----------------
__global__ __launch_bounds__(256) void colsum_k(const unsigned short* __restrict__ vbf,
                                                const float* __restrict__ rnrm,
                                                float* __restrict__ colsum, int Nn) {
  __shared__ float ls[256];
  int tid = threadIdx.x;
  int c = tid & 127, rsub = tid >> 7;
  float cs = 0.f;
  for (int r = blockIdx.x * 2 + rsub; r < Nn; r += gridDim.x * 2)
    cs += bf2f(vbf[(size_t)r * 128 + c]) * rnrm[r];
  ls[tid] = cs;
  __syncthreads();
  if (tid < 128) atomicAdd(&colsum[tid], ls[tid] + ls[tid + 128]);
}

// ---------------- final: mean over nodes of out2 ----------------
__global__ __launch_bounds__(256) void final_reduce(const float* __restrict__ out2,
                                                    float* __restrict__ outsum, int Nn) {
  __shared__ float ls[32];
  if (threadIdx.x < 32) ls[threadIdx.x] = 0.f;
  __syncthreads();
  int d = threadIdx.x & 31, rl = threadIdx.x >> 5;
  float acc = 0.f;
  for (int n = blockIdx.x * 8 + rl; n < Nn; n += gridDim.x * 8)
    acc += out2[(size_t)n * 32 + d];
  atomicAdd(&ls[d], acc);
  __syncthreads();
  if (threadIdx.x < 32) atomicAdd(&outsum[threadIdx.x], ls[threadIdx.x]);
}

__global__ void finalize_k(const float* __restrict__ outsum, float* __restrict__ out, float invN) {
  int t = threadIdx.x;
  if (t < 32) out[t] = outsum[t] * invN;
}

// ---------------- launcher ----------------
extern "C" void kernel_launch(void* const* d_in, const int* in_sizes, int n_in,
                              void* d_out, int out_size, void* d_ws, size_t ws_size,
                              hipStream_t stream) {
  const float* x     = (const float*)d_in[0];
  const int*   src   = (const int*)d_in[1];
  const int*   dst   = (const int*)d_in[2];
  const float* W0    = (const float*)d_in[3];
  const float* al0   = (const float*)d_in[4];
  const float* ar0   = (const float*)d_in[5];
  const float* W1    = (const float*)d_in[6];
  const float* al1   = (const float*)d_in[7];
  const float* ar1   = (const float*)d_in[8];
  const float* resW1 = (const float*)d_in[9];
  const float* W2    = (const float*)d_in[10];
  const float* al2   = (const float*)d_in[11];
  const float* ar2   = (const float*)d_in[12];
  const float* resW2 = (const float*)d_in[13];
  const int N = in_sizes[0] / 64;   // 100000
  const int E = in_sizes[1];        // 1600000
  const float invN = 1.f / (float)N;
  const int Emax = E + 15 * N + 1024;   // upper bound on padded slot count + margin
  const int NB = (N + 255) >> 8;        // dst buckets of 256 nodes (391)
  const int P2B = 256;                  // pass-2 block count
  const int chunk = (E + P2B - 1) / P2B;
  const int segN = NB * P2B;            // bucket-major segment table length

  char* p = (char*)d_ws;
  auto alloc = [&](size_t bytes) { char* r = p; p += (bytes + 255) & ~(size_t)255; return r; };

  // zero-initialized region
  char* zbase = p;
  int*   counts  = (int*)alloc((size_t)4 * N);
  float* colsumA = (float*)alloc(512);
  float* colsumB = (float*)alloc(512);
  float* outsum  = (float*)alloc(128);
  size_t zbytes = (size_t)(p - zbase);

  int* rsp   = (int*)alloc((size_t)4 * N);      // padded row starts
  int* bsum  = (int*)alloc(512);
  int* bhist = (int*)alloc((size_t)4 * segN);   // per-(bucket,block) counts -> seg (scanned in place)
  int* bsum2 = (int*)alloc(512);
  int2* ebuf = (int2*)alloc((size_t)8 * E);     // bucketed {src,dst}
  int* csr_src = (int*)alloc((size_t)4 * Emax); // memset 0: pads -> node 0, alpha 0
  unsigned char*  feat8 = (unsigned char*)alloc((size_t)N * 128);     // fp8 gather table
  unsigned short* vbf   = (unsigned short*)alloc((size_t)2 * N * 128);
  unsigned short* resh  = (unsigned short*)alloc((size_t)2 * N * 128);  // f16 residuals
  unsigned short* w0t = (unsigned short*)alloc((size_t)2 * 2 * 144 * 64);
  unsigned short* w1t = (unsigned short*)alloc((size_t)2 * 2 * 272 * 128);
  unsigned short* w2t = (unsigned short*)alloc((size_t)2 * 2 * 80 * 128);
  float* el4  = (float*)alloc((size_t)16 * N);
  float* er4  = (float*)alloc((size_t)16 * N);
  float* rnrm = (float*)alloc((size_t)4 * N);
  float* cmw1 = (float*)alloc(4 * 272);
  float* cmw2 = (float*)alloc(4 * 80);
  float* out2 = (float*)alloc((size_t)4 * N * 32);   // layer-2 output [N][32]

  hipMemsetAsync(zbase, 0, zbytes, stream);
  hipMemsetAsync(csr_src, 0, (size_t)4 * Emax, stream);

  // CSR build: degree hist + padded rsp scan
  int eb = (E + 255) / 256;
  int nb1024 = (N + 1023) / 1024;
  hist_k<<<eb, 256, 0, stream>>>(dst, counts, E);
  scan1<<<nb1024, 256, 0, stream>>>(counts, rsp, bsum, N);
  scan2<<<1, 128, 0, stream>>>(bsum, nb1024);
  scan3<<<(N + 255) / 256, 256, 0, stream>>>(rsp, bsum, N);

  // 3-pass bucketed counting-sort scatter (single-owner csr lines)
  int nb1024s = (segN + 1023) / 1024;
  bhist_k<<<P2B, 256, 0, stream>>>(dst, bhist, E, NB, chunk);
  pscan1<<<nb1024s, 256, 0, stream>>>(bhist, bhist, bsum2, segN);
  scan2<<<1, 128, 0, stream>>>(bsum2, nb1024s);
  scan3<<<(segN + 255) / 256, 256, 0, stream>>>(bhist, bsum2, segN);
  bscatter_k<<<P2B, 256, 0, stream>>>(src, dst, bhist, ebuf, E, NB, chunk);
  fscatter_k<<<NB, 256, 0, stream>>>(ebuf, bhist, rsp, csr_src, E, NB, P2B, N);

  // weights: [W | W@al | W@ar | pad | resW] transposed, bf16 hi+lo — one launch
  const int packTot = 144 * 64 + 272 * 128 + 80 * 128;
  fill_all<<<(packTot + 255) / 256, 256, 0, stream>>>(W0, al0, ar0, W1, al1, ar1, resW1,
                                                      W2, al2, ar2, resW2, w0t, w1t, w2t);

  const int rowTiles = N / 16;                  // 6250, divisible by R=5
  const int gblocks = (rowTiles / 5 + 3) / 4;   // 1250 waves, 4/block
  const int aggblocks = (N + 3) / 4;            // wave per node

  // Layer 0 (A = x fp32, no colmean fold)
  gemm_bf16<64, 144, 5, 128, 4, 144, true, false><<<gblocks, 256, 0, stream>>>(
      x, w0t, nullptr, feat8, el4, er4, nullptr, rowTiles);
  aggregate4<0><<<aggblocks, 256, 0, stream>>>(feat8, el4, er4, csr_src, rsp, counts, nullptr, vbf, rnrm, N);
  colsum_k<<<512, 256, 0, stream>>>(vbf, rnrm, colsumA, N);
  cmw_k<<<2, 256, 0, stream>>>(colsumA, w1t, cmw1, 128, 272, invN);

  // Layer 1 (A = vbf, colmean folded via cmw1)
  gemm_bf16<128, 272, 5, 128, 4, 144, false, true><<<gblocks, 256, 0, stream>>>(
      vbf, w1t, cmw1, feat8, el4, er4, resh, rowTiles);
  aggregate4<1><<<aggblocks, 256, 0, stream>>>(feat8, el4, er4, csr_src, rsp, counts, resh, vbf, rnrm, N);
  colsum_k<<<512, 256, 0, stream>>>(vbf, rnrm, colsumB, N);
  cmw_k<<<1, 256, 0, stream>>>(colsumB, w2t, cmw2, 128, 80, invN);

  // Layer 2 (A = vbf, colmean folded via cmw2)
  gemm_bf16<128, 80, 5, 32, 1, 48, false, true><<<gblocks, 256, 0, stream>>>(
      vbf, w2t, cmw2, feat8, el4, er4, resh, rowTiles);
  aggregate1<<<aggblocks, 256, 0, stream>>>(feat8, el4, er4, csr_src, rsp, counts, resh, out2, N);
  final_reduce<<<512, 256, 0, stream>>>(out2, outsum, N);
  finalize_k<<<1, 64, 0, stream>>>(outsum, (float*)d_out, invN);
}

// Round 3
// 565.538 us; speedup vs baseline: 1.1542x; 1.1542x over previous
//
#include <hip/hip_runtime.h>

// GAT 3-layer forward on MI355X — round 15.
// R13/R14 post-mortem: aggregate4's regime is GATHER-LATENCY-bound, not issue-bound.
// R12's strength was MLP=16: wave-uniform csr reads -> s_load_dwordx4, 16 independent
// feat8 loads in flight per chunk. Both restructures cut MLP to 4 -> slower despite
// fewer issue slots. R15 reverts aggregate4/aggregate1 to the R12 structure (only
// packing the 2 scalar FMAs into one v_pk_fma_f32) and instead attacks launch count:
//  - hist_k + bhist_k fused into hist2_k (one dst pass)
//  - scan1/scan2/scan3 + pscan1/scan2/scan3 fused into scanA/scanB (dual-array scan;
//    each scanB block redoes the tiny block-sum prefix locally)
//  - cmw_k folded into the GEMM prologue (cooperative LDS compute, barrier before
//    any early return)
// 25 dispatches -> 18.

typedef __attribute__((ext_vector_type(8))) short s8v;
typedef __attribute__((ext_vector_type(4))) float f4v;
typedef __attribute__((ext_vector_type(2))) float f2v;
typedef __attribute__((ext_vector_type(2))) _Float16 h2;
typedef __attribute__((ext_vector_type(4))) _Float16 h4;

__device__ __forceinline__ unsigned short f2bf(float f) {
  unsigned int x = __float_as_uint(f);
  x += 0x7fffu + ((x >> 16) & 1u);          // RTNE
  return (unsigned short)(x >> 16);
}
__device__ __forceinline__ float bf2f(unsigned short u) {
  return __uint_as_float(((unsigned int)u) << 16);
}
__device__ __forceinline__ unsigned short f2h(float f) {
  _Float16 h = (_Float16)f;
  return __builtin_bit_cast(unsigned short, h);
}
__device__ __forceinline__ unsigned char f2fp8(float v) {
  return (unsigned char)(__builtin_amdgcn_cvt_pk_fp8_f32(v, v, 0, false) & 0xff);
}
__device__ __forceinline__ float lrelu(float x) { return fmaxf(x, 0.2f * x); }
__device__ __forceinline__ float elu1(float x) { return x > 0.f ? x : expm1f(x); }

// ---------------- fused degree + bucket histogram (one dst pass) ----------------
__global__ __launch_bounds__(256) void hist2_k(const int* __restrict__ dst, int* __restrict__ counts,
                                               int* __restrict__ bhist, int E, int NB, int chunk) {
  __shared__ int h[512];
  for (int b = threadIdx.x; b < NB; b += 256) h[b] = 0;
  __syncthreads();
  int e0 = blockIdx.x * chunk;
  int e1 = min(E, e0 + chunk);
  for (int e = e0 + threadIdx.x; e < e1; e += 256) {
    int d = dst[e];
    atomicAdd(&counts[d], 1);
    atomicAdd(&h[d >> 8], 1);
  }
  __syncthreads();
  for (int b = threadIdx.x; b < NB; b += 256)
    bhist[(size_t)b * gridDim.x + blockIdx.x] = h[b];
}

// ---------------- dual-array scan, phase 1: per-block exclusive scan + block sums ----
// blocks [0,nbA): counts -> rsp with ROUND-UP-16 padding (row starts)
// blocks [nbA,..): bhist -> bhist in place (plain, bucket-segment table)
__global__ __launch_bounds__(256) void scanA(const int* __restrict__ counts, int* __restrict__ rsp,
                                             int* __restrict__ bsumA, int* __restrict__ bhist,
                                             int* __restrict__ bsumB, int NA, int NSEG, int nbA) {
  __shared__ int s[256];
  int t = threadIdx.x;
  bool isA = (int)blockIdx.x < nbA;
  int bb = isA ? (int)blockIdx.x : (int)blockIdx.x - nbA;
  const int* in = isA ? counts : bhist;
  int* out = isA ? rsp : bhist;
  int* bs = isA ? bsumA : bsumB;
  int Nn = isA ? NA : NSEG;
  int base = bb * 1024 + t * 4;
  int v0 = (base + 0 < Nn) ? in[base + 0] : 0;
  int v1 = (base + 1 < Nn) ? in[base + 1] : 0;
  int v2 = (base + 2 < Nn) ? in[base + 2] : 0;
  int v3 = (base + 3 < Nn) ? in[base + 3] : 0;
  if (isA) {
    v0 = (v0 + 15) & ~15;
    v1 = (v1 + 15) & ~15;
    v2 = (v2 + 15) & ~15;
    v3 = (v3 + 15) & ~15;
  }
  s[t] = v0 + v1 + v2 + v3;
  __syncthreads();
  for (int off = 1; off < 256; off <<= 1) {
    int xv = (t >= off) ? s[t - off] : 0;
    __syncthreads();
    s[t] += xv;
    __syncthreads();
  }
  int excl = t ? s[t - 1] : 0;
  if (t == 255) bs[bb] = s[255];
  if (base + 0 < Nn) { out[base + 0] = excl; excl += v0; }
  if (base + 1 < Nn) { out[base + 1] = excl; excl += v1; }
  if (base + 2 < Nn) { out[base + 2] = excl; excl += v2; }
  if (base + 3 < Nn) { out[base + 3] = excl; }
}

// ---------------- dual-array scan, phase 2: add block-sum prefixes ----------------
// each block re-scans its array's (small) block-sum vector locally, then adds.
__global__ __launch_bounds__(256) void scanB(int* __restrict__ rsp, const int* __restrict__ bsumA,
                                             int* __restrict__ bhist, const int* __restrict__ bsumB,
                                             int NA, int NSEG, int nbA, int nbB) {
  __shared__ int s[256];
  int t = threadIdx.x;
  bool isA = (int)blockIdx.x < nbA;
  int bb = isA ? (int)blockIdx.x : (int)blockIdx.x - nbA;
  int* arr = isA ? rsp : bhist;
  const int* bs = isA ? bsumA : bsumB;
  int nb = isA ? nbA : nbB;
  int Nn = isA ? NA : NSEG;
  s[t] = (t < nb) ? bs[t] : 0;
  __syncthreads();
  for (int off = 1; off < 256; off <<= 1) {
    int xv = (t >= off) ? s[t - off] : 0;
    __syncthreads();
    s[t] += xv;
    __syncthreads();
  }
  int pref = bb ? s[bb - 1] : 0;
  if (pref != 0) {
    int base = bb * 1024 + t * 4;
    if (base + 0 < Nn) arr[base + 0] += pref;
    if (base + 1 < Nn) arr[base + 1] += pref;
    if (base + 2 < Nn) arr[base + 2] += pref;
    if (base + 3 < Nn) arr[base + 3] += pref;
  }
}

// ---------------- pass 2: scatter edges into private (block,bucket) segments ----------------
__global__ __launch_bounds__(256) void bscatter_k(const int* __restrict__ src, const int* __restrict__ dst,
                                                  const int* __restrict__ seg, int2* __restrict__ ebuf,
                                                  int E, int NB, int chunk) {
  __shared__ int cur[512];
  for (int b = threadIdx.x; b < NB; b += 256)
    cur[b] = seg[(size_t)b * gridDim.x + blockIdx.x];
  __syncthreads();
  int e0 = blockIdx.x * chunk;
  int e1 = min(E, e0 + chunk);
  for (int e = e0 + threadIdx.x; e < e1; e += 256) {
    int d = dst[e];
    int pos = atomicAdd(&cur[d >> 8], 1);
    int2 v; v.x = src[e]; v.y = d;
    ebuf[pos] = v;
  }
}

// ---------------- pass 3: per-bucket final scatter (one block per 256-node bucket) ----------------
__global__ __launch_bounds__(256) void fscatter_k(const int2* __restrict__ ebuf, const int* __restrict__ seg,
                                                  const int* __restrict__ rsp, int* __restrict__ csr_src,
                                                  int E, int NB, int P2B, int Nn) {
  __shared__ int cur[256];
  int b = blockIdx.x;
  int node0 = b << 8;
  int node = node0 + threadIdx.x;
  if (node < Nn) cur[threadIdx.x] = rsp[node];
  __syncthreads();
  int bstart = seg[(size_t)b * P2B];
  int bend = (b + 1 < NB) ? seg[(size_t)(b + 1) * P2B] : E;
  for (int e = bstart + threadIdx.x; e < bend; e += 256) {
    int2 sd = ebuf[e];
    int pos = atomicAdd(&cur[sd.y - node0], 1);
    csr_src[pos] = sd.x;
  }
}

// ---------------- fused weight pack (all 3 layers, one launch) ----------------
__device__ __forceinline__ void pack_one(const float* W, const float* al, const float* ar,
                                         const float* resW, unsigned short* out,
                                         int K, int M, int BF, int H, int RES0, int t) {
  int c = t / K, k = t - c * K;
  float v = 0.f;
  if (c < BF) {
    v = W[k * BF + c];
  } else if (c < BF + H) {
    int h = c - BF;
    float s = 0.f;
    for (int d = 0; d < 32; d++) s += W[k * BF + h * 32 + d] * al[h * 32 + d];
    v = s;
  } else if (c < BF + 2 * H) {
    int h = c - BF - H;
    float s = 0.f;
    for (int d = 0; d < 32; d++) s += W[k * BF + h * 32 + d] * ar[h * 32 + d];
    v = s;
  } else if (c >= RES0) {
    v = resW[k * (M - RES0) + (c - RES0)];
  }
  unsigned short hi = f2bf(v);
  out[c * K + k] = hi;
  out[M * K + c * K + k] = f2bf(v - bf2f(hi));
}

__global__ __launch_bounds__(256) void fill_all(const float* __restrict__ W0, const float* __restrict__ al0,
                                                const float* __restrict__ ar0,
                                                const float* __restrict__ W1, const float* __restrict__ al1,
                                                const float* __restrict__ ar1, const float* __restrict__ resW1,
                                                const float* __restrict__ W2, const float* __restrict__ al2,
                                                const float* __restrict__ ar2, const float* __restrict__ resW2,
                                                unsigned short* __restrict__ w0t, unsigned short* __restrict__ w1t,
                                                unsigned short* __restrict__ w2t) {
  const int n0 = 144 * 64, n1 = 272 * 128, n2 = 80 * 128;
  int t = blockIdx.x * 256 + threadIdx.x;
  if (t < n0) {
    pack_one(W0, al0, ar0, nullptr, w0t, 64, 144, 128, 4, 144, t);
  } else if (t < n0 + n1) {
    pack_one(W1, al1, ar1, resW1, w1t, 128, 272, 128, 4, 144, t - n0);
  } else if (t < n0 + n1 + n2) {
    pack_one(W2, al2, ar2, resW2, w2t, 128, 80, 32, 1, 48, t - n0 - n1);
  }
}

// ---------------- GEMM: A[N,K] @ Bt[M,K](bf16 hi+lo); cmw fold computed in-kernel ----
template <int K, int M, int R, int BF, int H, int RES0, bool AF32, bool CMW>
__global__ __launch_bounds__(256) void gemm_bf16(const void* __restrict__ Av,
                                                 const unsigned short* __restrict__ Bt,
                                                 const float* __restrict__ colsum, float invN,
                                                 unsigned char* __restrict__ feat8,
                                                 float* __restrict__ el, float* __restrict__ er,
                                                 unsigned short* __restrict__ resh, int nRowTiles) {
  __shared__ float cmw_s[M];
  if constexpr (CMW) {
    // rank-1 PairNorm fold: cmw[c] = invN * sum_k colsum[k]*(Whi[c,k]+Wlo[c,k])
    for (int cc = threadIdx.x; cc < M; cc += 256) {
      float s = 0.f;
      for (int k = 0; k < K; k++)
        s += colsum[k] * (bf2f(Bt[cc * K + k]) + bf2f(Bt[(size_t)M * K + cc * K + k]));
      cmw_s[cc] = s * invN;
    }
    __syncthreads();   // before any early return: all waves participate
  }
  int wv = (int)((blockIdx.x * blockDim.x + threadIdx.x) >> 6);
  int tile0 = wv * R;
  if (tile0 >= nRowTiles) return;
  int lane = threadIdx.x & 63;
  int r = lane & 15, q = lane >> 4;
  s8v afrag[R][K / 32];
#pragma unroll
  for (int rr = 0; rr < R; rr++) {
    if constexpr (AF32) {
      const float* arow = (const float*)Av + (size_t)((tile0 + rr) * 16 + r) * K + q * 8;
#pragma unroll
      for (int kk = 0; kk < K / 32; kk++) {
        s8v v;
#pragma unroll
        for (int j = 0; j < 8; j++) v[j] = (short)f2bf(arow[kk * 32 + j]);
        afrag[rr][kk] = v;
      }
    } else {
      const unsigned short* arow = (const unsigned short*)Av + (size_t)((tile0 + rr) * 16 + r) * K + q * 8;
#pragma unroll
      for (int kk = 0; kk < K / 32; kk++) afrag[rr][kk] = *(const s8v*)(arow + kk * 32);
    }
  }
#pragma unroll
  for (int ct = 0; ct < M / 16; ct++) {
    const unsigned short* brow = Bt + (size_t)(ct * 16 + r) * K + q * 8;
    s8v bhi[K / 32], blo[K / 32];
#pragma unroll
    for (int kk = 0; kk < K / 32; kk++) {
      bhi[kk] = *(const s8v*)(brow + kk * 32);
      blo[kk] = *(const s8v*)(brow + (size_t)M * K + kk * 32);
    }
    int col = ct * 16 + r;
    float cmwv = 0.f;
    if constexpr (CMW) cmwv = cmw_s[col];
#pragma unroll
    for (int rr = 0; rr < R; rr++) {
      f4v acc = {0.f, 0.f, 0.f, 0.f};
#pragma unroll
      for (int kk = 0; kk < K / 32; kk++) {
        acc = __builtin_amdgcn_mfma_f32_16x16x32_bf16(afrag[rr][kk], bhi[kk], acc, 0, 0, 0);
        acc = __builtin_amdgcn_mfma_f32_16x16x32_bf16(afrag[rr][kk], blo[kk], acc, 0, 0, 0);
      }
      int row0 = (tile0 + rr) * 16 + q * 4;
#pragma unroll
      for (int i = 0; i < 4; i++) {
        float v = acc[i] - cmwv;
        size_t row = (size_t)(row0 + i);
        if (col < BF) {
          feat8[row * BF + col] = f2fp8(v);
        } else if (col < BF + H) {
          el[row * H + (col - BF)] = v;
        } else if (col < BF + 2 * H) {
          er[row * H + (col - BF - H)] = v;
        } else if (RES0 < M && col >= RES0) {
          resh[row * (M - RES0) + (col - RES0)] = f2h(v);
        }
      }
    }
  }
}

// ---------------- fused single-pass aggregation H=4 (fp8 feat table) ----------------
// R12 structure (MLP=16: wave-uniform csr batch -> s_load, 16 independent 2B feat
// loads in flight). Only change vs R12: f2v accumulator + v_pk_fma_f32.
template <int MODE>
__global__ __launch_bounds__(256) void aggregate4(const unsigned char* __restrict__ feat8,
                                                  const float* __restrict__ el4,
                                                  const float* __restrict__ er4,
                                                  const int* __restrict__ csr_src,
                                                  const int* __restrict__ rsp,
                                                  const int* __restrict__ counts,
                                                  const unsigned short* __restrict__ resh,
                                                  unsigned short* __restrict__ vbf,
                                                  float* __restrict__ rnrm, int Nn) {
  int n = (int)((blockIdx.x * blockDim.x + threadIdx.x) >> 6);
  if (n >= Nn) return;
  int lane = threadIdx.x & 63;
  int start = __builtin_amdgcn_readfirstlane(rsp[n]);
  int deg = __builtin_amdgcn_readfirstlane(counts[n]);
  int chunks = (deg + 15) >> 4;
  int slot = lane >> 2, h = lane & 3;
  float ern = er4[(size_t)n * 4 + h];
  int hl = lane >> 4;                        // head of lane's dims (dims 2l..2l+1)
  unsigned dby = (unsigned)lane << 1;        // byte offset into 128B fp8 row
  f2v a01 = {0.f, 0.f};
  float dsum = 0.f;
  for (int c = 0; c < chunks; c++) {
    const int* csp = csr_src + start + (c << 4);
    // phase A: one (edge,head) per lane
    int sA = csp[slot];
    float exv = 0.f;
    if (((c << 4) + slot) < deg) {
      float e = el4[(size_t)sA * 4 + h] + ern;
      exv = __expf(fmaxf(e, 0.2f * e));
    }
    dsum += exv;
    // phase B: batch all 16 csr reads first (wave-uniform -> scalar loads, 16 MLP)
    int sj[16];
#pragma unroll
    for (int j = 0; j < 16; j++) sj[j] = csp[j];
#pragma unroll
    for (int j = 0; j < 16; j++) {
      float aw = __shfl(exv, (j << 2) | hl);
      unsigned short u = *(const unsigned short*)(feat8 + (((unsigned)sj[j] << 7) + dby));
      f2v fv = __builtin_amdgcn_cvt_pk_f32_fp8((int)u, false);
      f2v aw2 = {aw, aw};
      a01 = __builtin_elementwise_fma(fv, aw2, a01);
    }
  }
  // per-head denominator totals: after butterfly, lane l holds head (l&3) total
#pragma unroll
  for (int off = 4; off < 64; off <<= 1) dsum += __shfl_xor(dsum, off);
  float inv = dsum > 0.f ? 1.f / dsum : 0.f;
  float invh = __shfl(inv, hl);
  float v0, v1;
  if (MODE == 1) {
    h2 rr = *(const h2*)(resh + (size_t)n * 128 + lane * 2);
    v0 = elu1(elu1(a01[0] * invh + (float)rr[0]));
    v1 = elu1(elu1(a01[1] * invh + (float)rr[1]));
  } else {
    v0 = elu1(a01[0] * invh);
    v1 = elu1(a01[1] * invh);
  }
  float ss = v0 * v0 + v1 * v1;
#pragma unroll
  for (int off = 1; off < 64; off <<= 1) ss += __shfl_xor(ss, off);
  float rn = sqrtf(1e-6f + ss);
  float ri = 1.f / rn;
  unsigned int pk = (unsigned int)f2bf(v0 * ri) | ((unsigned int)f2bf(v1 * ri) << 16);
  *(unsigned int*)((char*)vbf + ((size_t)n << 8) + (lane << 2)) = pk;
  if (lane == 0) rnrm[n] = rn;
}

// ---------------- fused single-pass aggregation H=1 (layer 2, fp8 table) ----------------
// R12 structure; packed fma only.
__global__ __launch_bounds__(256) void aggregate1(const unsigned char* __restrict__ feat8,
                                                  const float* __restrict__ el1,
                                                  const float* __restrict__ er1,
                                                  const int* __restrict__ csr_src,
                                                  const int* __restrict__ rsp,
                                                  const int* __restrict__ counts,
                                                  const unsigned short* __restrict__ res2h,
                                                  float* __restrict__ out2, int Nn) {
  int n = (int)((blockIdx.x * blockDim.x + threadIdx.x) >> 6);
  if (n >= Nn) return;
  int lane = threadIdx.x & 63;
  int start = __builtin_amdgcn_readfirstlane(rsp[n]);
  int deg = __builtin_amdgcn_readfirstlane(counts[n]);
  int chunks = (deg + 15) >> 4;
  int l16 = lane & 15;
  float ern = er1[n];
  int g = lane >> 3;                          // 8 edge groups (2 edges each per chunk)
  unsigned dofs4 = (unsigned)(lane & 7) << 2; // byte offset into 32B fp8 row
  f2v acc01 = {0.f, 0.f}, acc23 = {0.f, 0.f};
  float dsum = 0.f;
  for (int c = 0; c < chunks; c++) {
    const int* csp = csr_src + start + (c << 4);
    int sA = csp[l16];
    float exv = 0.f;
    if (((c << 4) + l16) < deg) exv = __expf(lrelu(el1[sA] + ern));
    dsum += exv;
#pragma unroll
    for (int t = 0; t < 2; t++) {
      int j = (t << 3) + g;
      int sj = __shfl(sA, j);
      float aw = __shfl(exv, j);
      f2v aw2 = {aw, aw};
      unsigned int u = *(const unsigned int*)(feat8 + (((unsigned)sj << 5) + dofs4));
      f2v fa = __builtin_amdgcn_cvt_pk_f32_fp8((int)u, false);
      f2v fb = __builtin_amdgcn_cvt_pk_f32_fp8((int)u, true);
      acc01 = __builtin_elementwise_fma(fa, aw2, acc01);
      acc23 = __builtin_elementwise_fma(fb, aw2, acc23);
    }
  }
#pragma unroll
  for (int off = 1; off < 16; off <<= 1) dsum += __shfl_xor(dsum, off);
  float inv = dsum > 0.f ? 1.f / dsum : 0.f;
#pragma unroll
  for (int off = 8; off < 64; off <<= 1) {
    acc01[0] += __shfl_xor(acc01[0], off);
    acc01[1] += __shfl_xor(acc01[1], off);
    acc23[0] += __shfl_xor(acc23[0], off);
    acc23[1] += __shfl_xor(acc23[1], off);
  }
  if (lane < 8) {
    h4 rr = *(const h4*)(res2h + (size_t)n * 32 + (lane << 2));
    float4 o;
    o.x = acc01[0] * inv + (float)rr[0];
    o.y = acc01[1] * inv + (float)rr[1];
    o.z = acc23[0] * inv + (float)rr[2];
    o.w = acc23[1] * inv + (float)rr[3];
    *(float4*)(out2 + (size_t)n * 32 + (lane << 2)) = o;
  }
}

// ---------------- colsum of raw v = vbf * rnrm (PairNorm colmean numerator) ----------------
__global__ __launch_bounds__(256) void colsum_k(const unsigned short* __restrict__ vbf,
                                                const float* __restrict__ rnrm,
                                                float* __restrict__ colsum, int Nn) {
  __shared__ float ls[256];
  int tid = threadIdx.x;
  int c = tid & 127, rsub = tid >> 7;
  float cs = 0.f;
  for (int r = blockIdx.x * 2 + rsub; r < Nn; r += gridDim.x * 2)
    cs += bf2f(vbf[(size_t)r * 128 + c]) * rnrm[r];
  ls[tid] = cs;
  __syncthreads();
  if (tid < 128) atomicAdd(&colsum[tid], ls[tid] + ls[tid + 128]);
}

// ---------------- final: mean over nodes of out2 ----------------
__global__ __launch_bounds__(256) void final_reduce(const float* __restrict__ out2,
                                                    float* __restrict__ outsum, int Nn) {
  __shared__ float ls[32];
  if (threadIdx.x < 32) ls[threadIdx.x] = 0.f;
  __syncthreads();
  int d = threadIdx.x & 31, rl = threadIdx.x >> 5;
  float acc = 0.f;
  for (int n = blockIdx.x * 8 + rl; n < Nn; n += gridDim.x * 8)
    acc += out2[(size_t)n * 32 + d];
  atomicAdd(&ls[d], acc);
  __syncthreads();
  if (threadIdx.x < 32) atomicAdd(&outsum[threadIdx.x], ls[threadIdx.x]);
}

__global__ void finalize_k(const float* __restrict__ outsum, float* __restrict__ out, float invN) {
  int t = threadIdx.x;
  if (t < 32) out[t] = outsum[t] * invN;
}

// ---------------- launcher ----------------
extern "C" void kernel_launch(void* const* d_in, const int* in_sizes, int n_in,
                              void* d_out, int out_size, void* d_ws, size_t ws_size,
                              hipStream_t stream) {
  const float* x     = (const float*)d_in[0];
  const int*   src   = (const int*)d_in[1];
  const int*   dst   = (const int*)d_in[2];
  const float* W0    = (const float*)d_in[3];
  const float* al0   = (const float*)d_in[4];
  const float* ar0   = (const float*)d_in[5];
  const float* W1    = (const float*)d_in[6];
  const float* al1   = (const float*)d_in[7];
  const float* ar1   = (const float*)d_in[8];
  const float* resW1 = (const float*)d_in[9];
  const float* W2    = (const float*)d_in[10];
  const float* al2   = (const float*)d_in[11];
  const float* ar2   = (const float*)d_in[12];
  const float* resW2 = (const float*)d_in[13];
  const int N = in_sizes[0] / 64;   // 100000
  const int E = in_sizes[1];        // 1600000
  const float invN = 1.f / (float)N;
  const int Emax = E + 15 * N + 1024;   // upper bound on padded slot count + margin
  const int NB = (N + 255) >> 8;        // dst buckets of 256 nodes (391)
  const int P2B = 512;                  // histogram/scatter block count
  const int chunk = (E + P2B - 1) / P2B;
  const int segN = NB * P2B;            // bucket-major segment table length
  const int nbA = (N + 1023) / 1024;    // scan blocks for rsp array (98)
  const int nbB = (segN + 1023) / 1024; // scan blocks for segment table (196)

  char* p = (char*)d_ws;
  auto alloc = [&](size_t bytes) { char* r = p; p += (bytes + 255) & ~(size_t)255; return r; };

  // zero-initialized region
  char* zbase = p;
  int*   counts  = (int*)alloc((size_t)4 * N);
  float* colsumA = (float*)alloc(512);
  float* colsumB = (float*)alloc(512);
  float* outsum  = (float*)alloc(128);
  size_t zbytes = (size_t)(p - zbase);

  int* rsp   = (int*)alloc((size_t)4 * N);      // padded row starts
  int* bsumA = (int*)alloc(1024);
  int* bhist = (int*)alloc((size_t)4 * segN);   // per-(bucket,block) counts -> seg (scanned in place)
  int* bsumB = (int*)alloc(1024);
  int2* ebuf = (int2*)alloc((size_t)8 * E);     // bucketed {src,dst}
  int* csr_src = (int*)alloc((size_t)4 * Emax); // memset 0: pads -> node 0, alpha 0
  unsigned char*  feat8 = (unsigned char*)alloc((size_t)N * 128);     // fp8 gather table
  unsigned short* vbf   = (unsigned short*)alloc((size_t)2 * N * 128);
  unsigned short* resh  = (unsigned short*)alloc((size_t)2 * N * 128);  // f16 residuals
  unsigned short* w0t = (unsigned short*)alloc((size_t)2 * 2 * 144 * 64);
  unsigned short* w1t = (unsigned short*)alloc((size_t)2 * 2 * 272 * 128);
  unsigned short* w2t = (unsigned short*)alloc((size_t)2 * 2 * 80 * 128);
  float* el4  = (float*)alloc((size_t)16 * N);
  float* er4  = (float*)alloc((size_t)16 * N);
  float* rnrm = (float*)alloc((size_t)4 * N);
  float* out2 = (float*)alloc((size_t)4 * N * 32);   // layer-2 output [N][32]

  hipMemsetAsync(zbase, 0, zbytes, stream);
  hipMemsetAsync(csr_src, 0, (size_t)4 * Emax, stream);

  // CSR build: fused histograms -> fused dual scan -> bucket scatter -> final scatter
  hist2_k<<<P2B, 256, 0, stream>>>(dst, counts, bhist, E, NB, chunk);
  scanA<<<nbA + nbB, 256, 0, stream>>>(counts, rsp, bsumA, bhist, bsumB, N, segN, nbA);
  scanB<<<nbA + nbB, 256, 0, stream>>>(rsp, bsumA, bhist, bsumB, N, segN, nbA, nbB);
  bscatter_k<<<P2B, 256, 0, stream>>>(src, dst, bhist, ebuf, E, NB, chunk);
  fscatter_k<<<NB, 256, 0, stream>>>(ebuf, bhist, rsp, csr_src, E, NB, P2B, N);

  // weights: [W | W@al | W@ar | pad | resW] transposed, bf16 hi+lo — one launch
  const int packTot = 144 * 64 + 272 * 128 + 80 * 128;
  fill_all<<<(packTot + 255) / 256, 256, 0, stream>>>(W0, al0, ar0, W1, al1, ar1, resW1,
                                                      W2, al2, ar2, resW2, w0t, w1t, w2t);

  const int rowTiles = N / 16;                  // 6250, divisible by R=5
  const int gblocks = (rowTiles / 5 + 3) / 4;   // 1250 waves, 4/block
  const int aggblocks = (N + 3) / 4;            // wave per node

  // Layer 0 (A = x fp32, no colmean fold)
  gemm_bf16<64, 144, 5, 128, 4, 144, true, false><<<gblocks, 256, 0, stream>>>(
      x, w0t, nullptr, invN, feat8, el4, er4, nullptr, rowTiles);
  aggregate4<0><<<aggblocks, 256, 0, stream>>>(feat8, el4, er4, csr_src, rsp, counts, nullptr, vbf, rnrm, N);
  colsum_k<<<512, 256, 0, stream>>>(vbf, rnrm, colsumA, N);

  // Layer 1 (A = vbf, colmean folded in-kernel from colsumA)
  gemm_bf16<128, 272, 5, 128, 4, 144, false, true><<<gblocks, 256, 0, stream>>>(
      vbf, w1t, colsumA, invN, feat8, el4, er4, resh, rowTiles);
  aggregate4<1><<<aggblocks, 256, 0, stream>>>(feat8, el4, er4, csr_src, rsp, counts, resh, vbf, rnrm, N);
  colsum_k<<<512, 256, 0, stream>>>(vbf, rnrm, colsumB, N);

  // Layer 2 (A = vbf, colmean folded in-kernel from colsumB)
  gemm_bf16<128, 80, 5, 32, 1, 48, false, true><<<gblocks, 256, 0, stream>>>(
      vbf, w2t, colsumB, invN, feat8, el4, er4, resh, rowTiles);
  aggregate1<<<aggblocks, 256, 0, stream>>>(feat8, el4, er4, csr_src, rsp, counts, resh, out2, N);
  final_reduce<<<512, 256, 0, stream>>>(out2, outsum, N);
  finalize_k<<<1, 64, 0, stream>>>(outsum, (float*)d_out, invN);
}

// Round 4
// 546.127 us; speedup vs baseline: 1.1953x; 1.0355x over previous
//
#include <hip/hip_runtime.h>

// GAT 3-layer forward on MI355X — round 16.
// vs round 15 (565.5us): keep R15 structure (it matched prediction). Changes:
//  - aggregate4/aggregate1: software-pipeline the per-chunk el-gather chain
//    (csr[slot] -> el[] gather -> exp) by prefetching chunk c+1's gather during
//    chunk c's FMA phase. Per-chunk memory pattern unchanged from the proven R12
//    form (wave-uniform sj batch -> SGPR feat addresses, shfl for multiplier only).
//  - elu1 via __expf(x)-1 (was libm expm1f, ~25 ops; error ~1e-7 << tolerance).
//  - ebuf packed to 4B: (src<<8)|(dst&255) — 25 bits; halves bscatter write +
//    fscatter read traffic.
//  - fill_all merged into the histogram launch (role-split grid) — one fewer
//    serialization point.

typedef __attribute__((ext_vector_type(8))) short s8v;
typedef __attribute__((ext_vector_type(4))) float f4v;
typedef __attribute__((ext_vector_type(2))) float f2v;
typedef __attribute__((ext_vector_type(2))) _Float16 h2;
typedef __attribute__((ext_vector_type(4))) _Float16 h4;

__device__ __forceinline__ unsigned short f2bf(float f) {
  unsigned int x = __float_as_uint(f);
  x += 0x7fffu + ((x >> 16) & 1u);          // RTNE
  return (unsigned short)(x >> 16);
}
__device__ __forceinline__ float bf2f(unsigned short u) {
  return __uint_as_float(((unsigned int)u) << 16);
}
__device__ __forceinline__ unsigned short f2h(float f) {
  _Float16 h = (_Float16)f;
  return __builtin_bit_cast(unsigned short, h);
}
__device__ __forceinline__ unsigned char f2fp8(float v) {
  return (unsigned char)(__builtin_amdgcn_cvt_pk_fp8_f32(v, v, 0, false) & 0xff);
}
__device__ __forceinline__ float lrelu(float x) { return fmaxf(x, 0.2f * x); }
__device__ __forceinline__ float elu1(float x) { return x > 0.f ? x : __expf(x) - 1.f; }

// ---------------- fused degree + bucket histogram + weight pack (one launch) ----------
__device__ __forceinline__ void pack_one(const float* W, const float* al, const float* ar,
                                         const float* resW, unsigned short* out,
                                         int K, int M, int BF, int H, int RES0, int t) {
  int c = t / K, k = t - c * K;
  float v = 0.f;
  if (c < BF) {
    v = W[k * BF + c];
  } else if (c < BF + H) {
    int h = c - BF;
    float s = 0.f;
    for (int d = 0; d < 32; d++) s += W[k * BF + h * 32 + d] * al[h * 32 + d];
    v = s;
  } else if (c < BF + 2 * H) {
    int h = c - BF - H;
    float s = 0.f;
    for (int d = 0; d < 32; d++) s += W[k * BF + h * 32 + d] * ar[h * 32 + d];
    v = s;
  } else if (c >= RES0) {
    v = resW[k * (M - RES0) + (c - RES0)];
  }
  unsigned short hi = f2bf(v);
  out[c * K + k] = hi;
  out[M * K + c * K + k] = f2bf(v - bf2f(hi));
}

__global__ __launch_bounds__(256) void hist_pack_k(const int* __restrict__ dst, int* __restrict__ counts,
                                                   int* __restrict__ bhist, int E, int NB, int chunk, int P2B,
                                                   const float* __restrict__ W0, const float* __restrict__ al0,
                                                   const float* __restrict__ ar0,
                                                   const float* __restrict__ W1, const float* __restrict__ al1,
                                                   const float* __restrict__ ar1, const float* __restrict__ resW1,
                                                   const float* __restrict__ W2, const float* __restrict__ al2,
                                                   const float* __restrict__ ar2, const float* __restrict__ resW2,
                                                   unsigned short* __restrict__ w0t, unsigned short* __restrict__ w1t,
                                                   unsigned short* __restrict__ w2t) {
  if ((int)blockIdx.x < P2B) {
    __shared__ int h[512];
    for (int b = threadIdx.x; b < NB; b += 256) h[b] = 0;
    __syncthreads();
    int e0 = blockIdx.x * chunk;
    int e1 = min(E, e0 + chunk);
    for (int e = e0 + threadIdx.x; e < e1; e += 256) {
      int d = dst[e];
      atomicAdd(&counts[d], 1);
      atomicAdd(&h[d >> 8], 1);
    }
    __syncthreads();
    for (int b = threadIdx.x; b < NB; b += 256)
      bhist[(size_t)b * P2B + blockIdx.x] = h[b];
  } else {
    const int n0 = 144 * 64, n1 = 272 * 128, n2 = 80 * 128;
    int t = ((int)blockIdx.x - P2B) * 256 + threadIdx.x;
    if (t < n0) {
      pack_one(W0, al0, ar0, nullptr, w0t, 64, 144, 128, 4, 144, t);
    } else if (t < n0 + n1) {
      pack_one(W1, al1, ar1, resW1, w1t, 128, 272, 128, 4, 144, t - n0);
    } else if (t < n0 + n1 + n2) {
      pack_one(W2, al2, ar2, resW2, w2t, 128, 80, 32, 1, 48, t - n0 - n1);
    }
  }
}

// ---------------- dual-array scan, phase 1: per-block exclusive scan + block sums ----
// blocks [0,nbA): counts -> rsp with ROUND-UP-16 padding (row starts)
// blocks [nbA,..): bhist -> bhist in place (plain, bucket-segment table)
__global__ __launch_bounds__(256) void scanA(const int* __restrict__ counts, int* __restrict__ rsp,
                                             int* __restrict__ bsumA, int* __restrict__ bhist,
                                             int* __restrict__ bsumB, int NA, int NSEG, int nbA) {
  __shared__ int s[256];
  int t = threadIdx.x;
  bool isA = (int)blockIdx.x < nbA;
  int bb = isA ? (int)blockIdx.x : (int)blockIdx.x - nbA;
  const int* in = isA ? counts : bhist;
  int* out = isA ? rsp : bhist;
  int* bs = isA ? bsumA : bsumB;
  int Nn = isA ? NA : NSEG;
  int base = bb * 1024 + t * 4;
  int v0 = (base + 0 < Nn) ? in[base + 0] : 0;
  int v1 = (base + 1 < Nn) ? in[base + 1] : 0;
  int v2 = (base + 2 < Nn) ? in[base + 2] : 0;
  int v3 = (base + 3 < Nn) ? in[base + 3] : 0;
  if (isA) {
    v0 = (v0 + 15) & ~15;
    v1 = (v1 + 15) & ~15;
    v2 = (v2 + 15) & ~15;
    v3 = (v3 + 15) & ~15;
  }
  s[t] = v0 + v1 + v2 + v3;
  __syncthreads();
  for (int off = 1; off < 256; off <<= 1) {
    int xv = (t >= off) ? s[t - off] : 0;
    __syncthreads();
    s[t] += xv;
    __syncthreads();
  }
  int excl = t ? s[t - 1] : 0;
  if (t == 255) bs[bb] = s[255];
  if (base + 0 < Nn) { out[base + 0] = excl; excl += v0; }
  if (base + 1 < Nn) { out[base + 1] = excl; excl += v1; }
  if (base + 2 < Nn) { out[base + 2] = excl; excl += v2; }
  if (base + 3 < Nn) { out[base + 3] = excl; }
}

// ---------------- dual-array scan, phase 2: add block-sum prefixes ----------------
__global__ __launch_bounds__(256) void scanB(int* __restrict__ rsp, const int* __restrict__ bsumA,
                                             int* __restrict__ bhist, const int* __restrict__ bsumB,
                                             int NA, int NSEG, int nbA, int nbB) {
  __shared__ int s[256];
  int t = threadIdx.x;
  bool isA = (int)blockIdx.x < nbA;
  int bb = isA ? (int)blockIdx.x : (int)blockIdx.x - nbA;
  int* arr = isA ? rsp : bhist;
  const int* bs = isA ? bsumA : bsumB;
  int nb = isA ? nbA : nbB;
  int Nn = isA ? NA : NSEG;
  s[t] = (t < nb) ? bs[t] : 0;
  __syncthreads();
  for (int off = 1; off < 256; off <<= 1) {
    int xv = (t >= off) ? s[t - off] : 0;
    __syncthreads();
    s[t] += xv;
    __syncthreads();
  }
  int pref = bb ? s[bb - 1] : 0;
  if (pref != 0) {
    int base = bb * 1024 + t * 4;
    if (base + 0 < Nn) arr[base + 0] += pref;
    if (base + 1 < Nn) arr[base + 1] += pref;
    if (base + 2 < Nn) arr[base + 2] += pref;
    if (base + 3 < Nn) arr[base + 3] += pref;
  }
}

// ---------------- pass 2: scatter edges into private (block,bucket) segments --------
// ebuf entry: (src << 8) | (dst & 255) — 25 bits used.
__global__ __launch_bounds__(256) void bscatter_k(const int* __restrict__ src, const int* __restrict__ dst,
                                                  const int* __restrict__ seg, unsigned int* __restrict__ ebuf,
                                                  int E, int NB, int chunk) {
  __shared__ int cur[512];
  for (int b = threadIdx.x; b < NB; b += 256)
    cur[b] = seg[(size_t)b * gridDim.x + blockIdx.x];
  __syncthreads();
  int e0 = blockIdx.x * chunk;
  int e1 = min(E, e0 + chunk);
  for (int e = e0 + threadIdx.x; e < e1; e += 256) {
    int d = dst[e];
    int pos = atomicAdd(&cur[d >> 8], 1);
    ebuf[pos] = ((unsigned int)src[e] << 8) | (unsigned int)(d & 255);
  }
}

// ---------------- pass 3: per-bucket final scatter (one block per 256-node bucket) ---
__global__ __launch_bounds__(256) void fscatter_k(const unsigned int* __restrict__ ebuf,
                                                  const int* __restrict__ seg,
                                                  const int* __restrict__ rsp, int* __restrict__ csr_src,
                                                  int E, int NB, int P2B, int Nn) {
  __shared__ int cur[256];
  int b = blockIdx.x;
  int node0 = b << 8;
  int node = node0 + threadIdx.x;
  if (node < Nn) cur[threadIdx.x] = rsp[node];
  __syncthreads();
  int bstart = seg[(size_t)b * P2B];
  int bend = (b + 1 < NB) ? seg[(size_t)(b + 1) * P2B] : E;
  for (int e = bstart + threadIdx.x; e < bend; e += 256) {
    unsigned int sd = ebuf[e];
    int pos = atomicAdd(&cur[sd & 255u], 1);
    csr_src[pos] = (int)(sd >> 8);
  }
}

// ---------------- GEMM: A[N,K] @ Bt[M,K](bf16 hi+lo); cmw fold computed in-kernel ----
template <int K, int M, int R, int BF, int H, int RES0, bool AF32, bool CMW>
__global__ __launch_bounds__(256) void gemm_bf16(const void* __restrict__ Av,
                                                 const unsigned short* __restrict__ Bt,
                                                 const float* __restrict__ colsum, float invN,
                                                 unsigned char* __restrict__ feat8,
                                                 float* __restrict__ el, float* __restrict__ er,
                                                 unsigned short* __restrict__ resh, int nRowTiles) {
  __shared__ float cmw_s[M];
  if constexpr (CMW) {
    // rank-1 PairNorm fold: cmw[c] = invN * sum_k colsum[k]*(Whi[c,k]+Wlo[c,k])
    for (int cc = threadIdx.x; cc < M; cc += 256) {
      float s = 0.f;
      for (int k = 0; k < K; k++)
        s += colsum[k] * (bf2f(Bt[cc * K + k]) + bf2f(Bt[(size_t)M * K + cc * K + k]));
      cmw_s[cc] = s * invN;
    }
    __syncthreads();   // before any early return: all waves participate
  }
  int wv = (int)((blockIdx.x * blockDim.x + threadIdx.x) >> 6);
  int tile0 = wv * R;
  if (tile0 >= nRowTiles) return;
  int lane = threadIdx.x & 63;
  int r = lane & 15, q = lane >> 4;
  s8v afrag[R][K / 32];
#pragma unroll
  for (int rr = 0; rr < R; rr++) {
    if constexpr (AF32) {
      const float* arow = (const float*)Av + (size_t)((tile0 + rr) * 16 + r) * K + q * 8;
#pragma unroll
      for (int kk = 0; kk < K / 32; kk++) {
        s8v v;
#pragma unroll
        for (int j = 0; j < 8; j++) v[j] = (short)f2bf(arow[kk * 32 + j]);
        afrag[rr][kk] = v;
      }
    } else {
      const unsigned short* arow = (const unsigned short*)Av + (size_t)((tile0 + rr) * 16 + r) * K + q * 8;
#pragma unroll
      for (int kk = 0; kk < K / 32; kk++) afrag[rr][kk] = *(const s8v*)(arow + kk * 32);
    }
  }
#pragma unroll
  for (int ct = 0; ct < M / 16; ct++) {
    const unsigned short* brow = Bt + (size_t)(ct * 16 + r) * K + q * 8;
    s8v bhi[K / 32], blo[K / 32];
#pragma unroll
    for (int kk = 0; kk < K / 32; kk++) {
      bhi[kk] = *(const s8v*)(brow + kk * 32);
      blo[kk] = *(const s8v*)(brow + (size_t)M * K + kk * 32);
    }
    int col = ct * 16 + r;
    float cmwv = 0.f;
    if constexpr (CMW) cmwv = cmw_s[col];
#pragma unroll
    for (int rr = 0; rr < R; rr++) {
      f4v acc = {0.f, 0.f, 0.f, 0.f};
#pragma unroll
      for (int kk = 0; kk < K / 32; kk++) {
        acc = __builtin_amdgcn_mfma_f32_16x16x32_bf16(afrag[rr][kk], bhi[kk], acc, 0, 0, 0);
        acc = __builtin_amdgcn_mfma_f32_16x16x32_bf16(afrag[rr][kk], blo[kk], acc, 0, 0, 0);
      }
      int row0 = (tile0 + rr) * 16 + q * 4;
#pragma unroll
      for (int i = 0; i < 4; i++) {
        float v = acc[i] - cmwv;
        size_t row = (size_t)(row0 + i);
        if (col < BF) {
          feat8[row * BF + col] = f2fp8(v);
        } else if (col < BF + H) {
          el[row * H + (col - BF)] = v;
        } else if (col < BF + 2 * H) {
          er[row * H + (col - BF - H)] = v;
        } else if (RES0 < M && col >= RES0) {
          resh[row * (M - RES0) + (col - RES0)] = f2h(v);
        }
      }
    }
  }
}

// ---------------- fused single-pass aggregation H=4 (fp8 feat table) ----------------
// R12 memory structure (MLP=16) + software-pipelined el-gather: chunk c+1's
// csr[slot]->el4 gather issues during chunk c's FMA phase, hiding the deepest
// latency chain (csr -> el4 -> exp -> bpermute) for multi-chunk nodes.
template <int MODE>
__global__ __launch_bounds__(256) void aggregate4(const unsigned char* __restrict__ feat8,
                                                  const float* __restrict__ el4,
                                                  const float* __restrict__ er4,
                                                  const int* __restrict__ csr_src,
                                                  const int* __restrict__ rsp,
                                                  const int* __restrict__ counts,
                                                  const unsigned short* __restrict__ resh,
                                                  unsigned short* __restrict__ vbf,
                                                  float* __restrict__ rnrm, int Nn) {
  int n = (int)((blockIdx.x * blockDim.x + threadIdx.x) >> 6);
  if (n >= Nn) return;
  int lane = threadIdx.x & 63;
  int start = __builtin_amdgcn_readfirstlane(rsp[n]);
  int deg = __builtin_amdgcn_readfirstlane(counts[n]);
  int chunks = (deg + 15) >> 4;
  int slot = lane >> 2, h = lane & 3;
  float ern = er4[(size_t)n * 4 + h];
  int hl = lane >> 4;                        // head of lane's dims (dims 2l..2l+1)
  unsigned dby = (unsigned)lane << 1;        // byte offset into 128B fp8 row
  f2v a01 = {0.f, 0.f};
  float dsum = 0.f;
  // prologue: chunk 0's phase-A gather
  float elv = el4[(size_t)csr_src[start + slot] * 4 + h];
  for (int c = 0; c < chunks; c++) {
    const int* csp = csr_src + start + (c << 4);
    // batch all 16 csr reads (wave-uniform -> scalar loads, 16 feat loads in flight)
    int sj[16];
#pragma unroll
    for (int j = 0; j < 16; j++) sj[j] = csp[j];
    // phase A from pipelined gather
    float e = elv + ern;
    float exv = (((c << 4) + slot) < deg) ? __expf(fmaxf(e, 0.2f * e)) : 0.f;
    dsum += exv;
    // prefetch next chunk's gather — hides under this chunk's FMA phase
    if (c + 1 < chunks) elv = el4[(size_t)csp[16 + slot] * 4 + h];
#pragma unroll
    for (int j = 0; j < 16; j++) {
      float aw = __shfl(exv, (j << 2) | hl);
      unsigned short u = *(const unsigned short*)(feat8 + (((unsigned)sj[j] << 7) + dby));
      f2v fv = __builtin_amdgcn_cvt_pk_f32_fp8((int)u, false);
      f2v aw2 = {aw, aw};
      a01 = __builtin_elementwise_fma(fv, aw2, a01);
    }
  }
  // per-head denominator totals: after butterfly, lane l holds head (l&3) total
#pragma unroll
  for (int off = 4; off < 64; off <<= 1) dsum += __shfl_xor(dsum, off);
  float inv = dsum > 0.f ? 1.f / dsum : 0.f;
  float invh = __shfl(inv, hl);
  float v0, v1;
  if (MODE == 1) {
    h2 rr = *(const h2*)(resh + (size_t)n * 128 + lane * 2);
    v0 = elu1(elu1(a01[0] * invh + (float)rr[0]));
    v1 = elu1(elu1(a01[1] * invh + (float)rr[1]));
  } else {
    v0 = elu1(a01[0] * invh);
    v1 = elu1(a01[1] * invh);
  }
  float ss = v0 * v0 + v1 * v1;
#pragma unroll
  for (int off = 1; off < 64; off <<= 1) ss += __shfl_xor(ss, off);
  float rn = sqrtf(1e-6f + ss);
  float ri = 1.f / rn;
  unsigned int pk = (unsigned int)f2bf(v0 * ri) | ((unsigned int)f2bf(v1 * ri) << 16);
  *(unsigned int*)((char*)vbf + ((size_t)n << 8) + (lane << 2)) = pk;
  if (lane == 0) rnrm[n] = rn;
}

// ---------------- fused single-pass aggregation H=1 (layer 2, fp8 table) ----------------
// R12 structure + pipelined el-gather.
__global__ __launch_bounds__(256) void aggregate1(const unsigned char* __restrict__ feat8,
                                                  const float* __restrict__ el1,
                                                  const float* __restrict__ er1,
                                                  const int* __restrict__ csr_src,
                                                  const int* __restrict__ rsp,
                                                  const int* __restrict__ counts,
                                                  const unsigned short* __restrict__ res2h,
                                                  float* __restrict__ out2, int Nn) {
  int n = (int)((blockIdx.x * blockDim.x + threadIdx.x) >> 6);
  if (n >= Nn) return;
  int lane = threadIdx.x & 63;
  int start = __builtin_amdgcn_readfirstlane(rsp[n]);
  int deg = __builtin_amdgcn_readfirstlane(counts[n]);
  int chunks = (deg + 15) >> 4;
  int l16 = lane & 15;
  float ern = er1[n];
  int g = lane >> 3;                          // 8 edge groups (2 edges each per chunk)
  unsigned dofs4 = (unsigned)(lane & 7) << 2; // byte offset into 32B fp8 row
  f2v acc01 = {0.f, 0.f}, acc23 = {0.f, 0.f};
  float dsum = 0.f;
  // prologue: chunk 0's src + gather
  int sA = csr_src[start + l16];
  float elv = el1[sA];
  for (int c = 0; c < chunks; c++) {
    const int* csp = csr_src + start + (c << 4);
    float exv = (((c << 4) + l16) < deg) ? __expf(lrelu(elv + ern)) : 0.f;
    dsum += exv;
    int sAc = sA;                              // current chunk's src (address shuffles)
    if (c + 1 < chunks) {
      sA = csp[16 + l16];
      elv = el1[sA];
    }
#pragma unroll
    for (int t = 0; t < 2; t++) {
      int j = (t << 3) + g;
      int sj = __shfl(sAc, j);
      float aw = __shfl(exv, j);
      f2v aw2 = {aw, aw};
      unsigned int u = *(const unsigned int*)(feat8 + (((unsigned)sj << 5) + dofs4));
      f2v fa = __builtin_amdgcn_cvt_pk_f32_fp8((int)u, false);
      f2v fb = __builtin_amdgcn_cvt_pk_f32_fp8((int)u, true);
      acc01 = __builtin_elementwise_fma(fa, aw2, acc01);
      acc23 = __builtin_elementwise_fma(fb, aw2, acc23);
    }
  }
#pragma unroll
  for (int off = 1; off < 16; off <<= 1) dsum += __shfl_xor(dsum, off);
  float inv = dsum > 0.f ? 1.f / dsum : 0.f;
#pragma unroll
  for (int off = 8; off < 64; off <<= 1) {
    acc01[0] += __shfl_xor(acc01[0], off);
    acc01[1] += __shfl_xor(acc01[1], off);
    acc23[0] += __shfl_xor(acc23[0], off);
    acc23[1] += __shfl_xor(acc23[1], off);
  }
  if (lane < 8) {
    h4 rr = *(const h4*)(res2h + (size_t)n * 32 + (lane << 2));
    float4 o;
    o.x = acc01[0] * inv + (float)rr[0];
    o.y = acc01[1] * inv + (float)rr[1];
    o.z = acc23[0] * inv + (float)rr[2];
    o.w = acc23[1] * inv + (float)rr[3];
    *(float4*)(out2 + (size_t)n * 32 + (lane << 2)) = o;
  }
}

// ---------------- colsum of raw v = vbf * rnrm (PairNorm colmean numerator) ----------------
__global__ __launch_bounds__(256) void colsum_k(const unsigned short* __restrict__ vbf,
                                                const float* __restrict__ rnrm,
                                                float* __restrict__ colsum, int Nn) {
  __shared__ float ls[256];
  int tid = threadIdx.x;
  int c = tid & 127, rsub = tid >> 7;
  float cs = 0.f;
  for (int r = blockIdx.x * 2 + rsub; r < Nn; r += gridDim.x * 2)
    cs += bf2f(vbf[(size_t)r * 128 + c]) * rnrm[r];
  ls[tid] = cs;
  __syncthreads();
  if (tid < 128) atomicAdd(&colsum[tid], ls[tid] + ls[tid + 128]);
}

// ---------------- final: mean over nodes of out2 ----------------
__global__ __launch_bounds__(256) void final_reduce(const float* __restrict__ out2,
                                                    float* __restrict__ outsum, int Nn) {
  __shared__ float ls[32];
  if (threadIdx.x < 32) ls[threadIdx.x] = 0.f;
  __syncthreads();
  int d = threadIdx.x & 31, rl = threadIdx.x >> 5;
  float acc = 0.f;
  for (int n = blockIdx.x * 8 + rl; n < Nn; n += gridDim.x * 8)
    acc += out2[(size_t)n * 32 + d];
  atomicAdd(&ls[d], acc);
  __syncthreads();
  if (threadIdx.x < 32) atomicAdd(&outsum[threadIdx.x], ls[threadIdx.x]);
}

__global__ void finalize_k(const float* __restrict__ outsum, float* __restrict__ out, float invN) {
  int t = threadIdx.x;
  if (t < 32) out[t] = outsum[t] * invN;
}

// ---------------- launcher ----------------
extern "C" void kernel_launch(void* const* d_in, const int* in_sizes, int n_in,
                              void* d_out, int out_size, void* d_ws, size_t ws_size,
                              hipStream_t stream) {
  const float* x     = (const float*)d_in[0];
  const int*   src   = (const int*)d_in[1];
  const int*   dst   = (const int*)d_in[2];
  const float* W0    = (const float*)d_in[3];
  const float* al0   = (const float*)d_in[4];
  const float* ar0   = (const float*)d_in[5];
  const float* W1    = (const float*)d_in[6];
  const float* al1   = (const float*)d_in[7];
  const float* ar1   = (const float*)d_in[8];
  const float* resW1 = (const float*)d_in[9];
  const float* W2    = (const float*)d_in[10];
  const float* al2   = (const float*)d_in[11];
  const float* ar2   = (const float*)d_in[12];
  const float* resW2 = (const float*)d_in[13];
  const int N = in_sizes[0] / 64;   // 100000
  const int E = in_sizes[1];        // 1600000
  const float invN = 1.f / (float)N;
  const int Emax = E + 15 * N + 1024;   // upper bound on padded slot count + margin
  const int NB = (N + 255) >> 8;        // dst buckets of 256 nodes (391)
  const int P2B = 512;                  // histogram/scatter block count
  const int chunk = (E + P2B - 1) / P2B;
  const int segN = NB * P2B;            // bucket-major segment table length
  const int nbA = (N + 1023) / 1024;    // scan blocks for rsp array (98)
  const int nbB = (segN + 1023) / 1024; // scan blocks for segment table (196)

  char* p = (char*)d_ws;
  auto alloc = [&](size_t bytes) { char* r = p; p += (bytes + 255) & ~(size_t)255; return r; };

  // zero-initialized region
  char* zbase = p;
  int*   counts  = (int*)alloc((size_t)4 * N);
  float* colsumA = (float*)alloc(512);
  float* colsumB = (float*)alloc(512);
  float* outsum  = (float*)alloc(128);
  size_t zbytes = (size_t)(p - zbase);

  int* rsp   = (int*)alloc((size_t)4 * N);      // padded row starts
  int* bsumA = (int*)alloc(1024);
  int* bhist = (int*)alloc((size_t)4 * segN);   // per-(bucket,block) counts -> seg (scanned in place)
  int* bsumB = (int*)alloc(1024);
  unsigned int* ebuf = (unsigned int*)alloc((size_t)4 * E);  // packed (src<<8)|(dst&255)
  int* csr_src = (int*)alloc((size_t)4 * Emax); // memset 0: pads -> node 0, alpha 0
  unsigned char*  feat8 = (unsigned char*)alloc((size_t)N * 128);     // fp8 gather table
  unsigned short* vbf   = (unsigned short*)alloc((size_t)2 * N * 128);
  unsigned short* resh  = (unsigned short*)alloc((size_t)2 * N * 128);  // f16 residuals
  unsigned short* w0t = (unsigned short*)alloc((size_t)2 * 2 * 144 * 64);
  unsigned short* w1t = (unsigned short*)alloc((size_t)2 * 2 * 272 * 128);
  unsigned short* w2t = (unsigned short*)alloc((size_t)2 * 2 * 80 * 128);
  float* el4  = (float*)alloc((size_t)16 * N);
  float* er4  = (float*)alloc((size_t)16 * N);
  float* rnrm = (float*)alloc((size_t)4 * N);
  float* out2 = (float*)alloc((size_t)4 * N * 32);   // layer-2 output [N][32]

  hipMemsetAsync(zbase, 0, zbytes, stream);
  hipMemsetAsync(csr_src, 0, (size_t)4 * Emax, stream);

  // CSR build + weight pack: fused histogram/pack -> fused dual scan -> scatters
  const int packTot = 144 * 64 + 272 * 128 + 80 * 128;   // 54272
  const int packBlocks = (packTot + 255) / 256;          // 212
  hist_pack_k<<<P2B + packBlocks, 256, 0, stream>>>(dst, counts, bhist, E, NB, chunk, P2B,
                                                    W0, al0, ar0, W1, al1, ar1, resW1,
                                                    W2, al2, ar2, resW2, w0t, w1t, w2t);
  scanA<<<nbA + nbB, 256, 0, stream>>>(counts, rsp, bsumA, bhist, bsumB, N, segN, nbA);
  scanB<<<nbA + nbB, 256, 0, stream>>>(rsp, bsumA, bhist, bsumB, N, segN, nbA, nbB);
  bscatter_k<<<P2B, 256, 0, stream>>>(src, dst, bhist, ebuf, E, NB, chunk);
  fscatter_k<<<NB, 256, 0, stream>>>(ebuf, bhist, rsp, csr_src, E, NB, P2B, N);

  const int rowTiles = N / 16;                  // 6250, divisible by R=5
  const int gblocks = (rowTiles / 5 + 3) / 4;   // 1250 waves, 4/block
  const int aggblocks = (N + 3) / 4;            // wave per node

  // Layer 0 (A = x fp32, no colmean fold)
  gemm_bf16<64, 144, 5, 128, 4, 144, true, false><<<gblocks, 256, 0, stream>>>(
      x, w0t, nullptr, invN, feat8, el4, er4, nullptr, rowTiles);
  aggregate4<0><<<aggblocks, 256, 0, stream>>>(feat8, el4, er4, csr_src, rsp, counts, nullptr, vbf, rnrm, N);
  colsum_k<<<512, 256, 0, stream>>>(vbf, rnrm, colsumA, N);

  // Layer 1 (A = vbf, colmean folded in-kernel from colsumA)
  gemm_bf16<128, 272, 5, 128, 4, 144, false, true><<<gblocks, 256, 0, stream>>>(
      vbf, w1t, colsumA, invN, feat8, el4, er4, resh, rowTiles);
  aggregate4<1><<<aggblocks, 256, 0, stream>>>(feat8, el4, er4, csr_src, rsp, counts, resh, vbf, rnrm, N);
  colsum_k<<<512, 256, 0, stream>>>(vbf, rnrm, colsumB, N);

  // Layer 2 (A = vbf, colmean folded in-kernel from colsumB)
  gemm_bf16<128, 80, 5, 32, 1, 48, false, true><<<gblocks, 256, 0, stream>>>(
      vbf, w2t, colsumB, invN, feat8, el4, er4, resh, rowTiles);
  aggregate1<<<aggblocks, 256, 0, stream>>>(feat8, el4, er4, csr_src, rsp, counts, resh, out2, N);
  final_reduce<<<512, 256, 0, stream>>>(out2, outsum, N);
  finalize_k<<<1, 64, 0, stream>>>(outsum, (float*)d_out, invN);
}